// Round 1
// baseline (166.704 us; speedup 1.0000x reference)
//
#include <hip/hip_runtime.h>

#define NN 4096
#define NE 512
#define HD 64
#define NDIAG 129
#define HWIN 64

// ---------------------------------------------------------------------------
// Kernel 1: projections  Q|K|V = x @ W + b
// grid 512 (16 rows/block), block 192 (3 waves; wave w handles matrix w).
// x rows are read with wave-uniform addresses -> scalar (s_load_dwordx4) path.
// ---------------------------------------------------------------------------
__global__ __launch_bounds__(192) void proj_kernel(
    const float* __restrict__ x,
    const float* __restrict__ Wq, const float* __restrict__ bq,
    const float* __restrict__ Wk, const float* __restrict__ bk,
    const float* __restrict__ Wv, const float* __restrict__ bv,
    float* __restrict__ Qo, float* __restrict__ Ko, float* __restrict__ Vo)
{
    const int c = threadIdx.x;       // 0..191
    const int m = c >> 6;            // matrix id, wave-uniform
    const int d = c & 63;            // output dim
    const int r0 = blockIdx.x * 16;

    const float* __restrict__ Wm = (m == 0) ? Wq : (m == 1) ? Wk : Wv;
    const float* __restrict__ bm = (m == 0) ? bq : (m == 1) ? bk : bv;
    float* __restrict__ om       = (m == 0) ? Qo : (m == 1) ? Ko : Vo;

    float acc[16];
#pragma unroll
    for (int r = 0; r < 16; ++r) acc[r] = 0.f;

    const float4* __restrict__ xp4 = (const float4*)(x + (size_t)r0 * NE);

    for (int k4 = 0; k4 < NE / 4; ++k4) {
        const float w0 = Wm[(k4 * 4 + 0) * HD + d];
        const float w1 = Wm[(k4 * 4 + 1) * HD + d];
        const float w2 = Wm[(k4 * 4 + 2) * HD + d];
        const float w3 = Wm[(k4 * 4 + 3) * HD + d];
#pragma unroll
        for (int r = 0; r < 16; ++r) {
            const float4 xv = xp4[r * (NE / 4) + k4];   // wave-uniform -> s_load
            acc[r] += xv.x * w0 + xv.y * w1 + xv.z * w2 + xv.w * w3;
        }
    }
    const float bias = bm[d];
#pragma unroll
    for (int r = 0; r < 16; ++r)
        om[(size_t)(r0 + r) * HD + d] = acc[r] + bias;
}

// ---------------------------------------------------------------------------
// Kernel 2: Vsum[b,d] = sum over all 4096 rows of V[b,:,d]
// grid 2, block 1024 (16 row-groups x 64 dims), LDS tree combine.
// ---------------------------------------------------------------------------
__global__ __launch_bounds__(1024) void vsum_kernel(
    const float* __restrict__ V, float* __restrict__ Vsum)
{
    __shared__ float red[1024];
    const int b = blockIdx.x;
    const int t = threadIdx.x;
    const int d = t & 63;
    const int g = t >> 6;            // 0..15
    const float* __restrict__ Vb = V + (size_t)b * NN * HD;
    float acc = 0.f;
#pragma unroll 8
    for (int r = g; r < NN; r += 16)
        acc += Vb[(size_t)r * HD + d];
    red[t] = acc;
    __syncthreads();
    if (g == 0) {
        float s = 0.f;
#pragma unroll
        for (int i = 0; i < 16; ++i) s += red[i * 64 + d];
        Vsum[b * HD + d] = s;
    }
}

// ---------------------------------------------------------------------------
// Kernel 3: attention. grid 256 (b = blk>>7, 32 queries/block), block 256.
// out[q,:] = (Vsum + sum_j w[q][j]*V[j,:]) / (4096 + sum_j w[q][j]),
// w[q][j] = valid(n0+q+j-64) ? exp(Q_q . K_{n0+q+j-64}) - 1 : 0
//
// smem (floats):
//   [0,10880)      Ks[160][68]  (phase1)  /  pacc[4][32][68] (phase2 partials)
//   [10880,15632)  wt[132][36]  weights, j-major (transposed for b128 reads)
//   [15632,15760)  pden[4][32]  per-wave denominator partials
// 63040 B static LDS (< 64 KB).
// ---------------------------------------------------------------------------
__global__ __launch_bounds__(256) void attn_kernel(
    const float* __restrict__ Qf, const float* __restrict__ Kf,
    const float* __restrict__ Vf, const float* __restrict__ Vsum,
    float* __restrict__ out)
{
    __shared__ float smem[15760];
    const int tid = threadIdx.x;
    const int b  = blockIdx.x >> 7;
    const int n0 = (blockIdx.x & 127) * 32;

    const float* __restrict__ Qb = Qf + ((size_t)b * NN + n0) * HD;
    const float* __restrict__ Kb = Kf + (size_t)b * NN * HD;
    const float* __restrict__ Vb = Vf + (size_t)b * NN * HD;

    // ---- stage K rows n0-64 .. n0+95 (160 rows, zero-padded at edges) ----
    for (int i = tid; i < 160 * 16; i += 256) {
        const int l = i >> 4, d4 = i & 15;
        const int n = n0 - HWIN + l;
        float4 v = make_float4(0.f, 0.f, 0.f, 0.f);
        if (n >= 0 && n < NN)
            v = *(const float4*)(Kb + (size_t)n * HD + d4 * 4);
        *(float4*)(&smem[l * 68 + d4 * 4]) = v;
    }
    __syncthreads();

    // ---- phase 1: banded scores -> weights (S = Qtile(32x64) @ Kslab^T) ----
    {
        const int lg = tid & 31;      // l = lg*5+u, u<5  (covers 160 rows)
        const int qg = tid >> 5;      // q = qg*4+i, i<4  (covers 32 queries)
        float s[4][5];
#pragma unroll
        for (int i = 0; i < 4; ++i)
#pragma unroll
            for (int u = 0; u < 5; ++u) s[i][u] = 0.f;

#pragma unroll 4
        for (int d4 = 0; d4 < 16; ++d4) {
            float4 qv[4];
#pragma unroll
            for (int i = 0; i < 4; ++i)
                qv[i] = *(const float4*)(Qb + (qg * 4 + i) * HD + d4 * 4);
            float4 kv[5];
#pragma unroll
            for (int u = 0; u < 5; ++u)
                kv[u] = *(const float4*)(&smem[(lg * 5 + u) * 68 + d4 * 4]);
#pragma unroll
            for (int i = 0; i < 4; ++i)
#pragma unroll
                for (int u = 0; u < 5; ++u)
                    s[i][u] += qv[i].x * kv[u].x + qv[i].y * kv[u].y
                             + qv[i].z * kv[u].z + qv[i].w * kv[u].w;
        }
#pragma unroll
        for (int i = 0; i < 4; ++i)
#pragma unroll
            for (int u = 0; u < 5; ++u) {
                const int q = qg * 4 + i;
                const int l = lg * 5 + u;
                const int j = l - q;                 // diagonal index
                if (j >= 0 && j < NDIAG) {
                    const int key = n0 + l - HWIN;   // global key row
                    float w = 0.f;
                    if (key >= 0 && key < NN)
                        w = __expf(s[i][u]) - 1.f;
                    smem[10880 + j * 36 + q] = w;
                }
            }
    }
    __syncthreads();

    // ---- phase 2: partial out = w(32x129) @ V[0:129] , j-split over waves ----
    {
        const int wv = tid >> 6;          // wave 0..3
        const int lane = tid & 63;
        const int qg2 = lane >> 3;        // q = qg2*4+i
        const int dg = lane & 7;          // d = dg*8+u
        float acc[4][8];
        float dacc[4];
#pragma unroll
        for (int i = 0; i < 4; ++i) {
            dacc[i] = 0.f;
#pragma unroll
            for (int u = 0; u < 8; ++u) acc[i][u] = 0.f;
        }
        for (int jj = 0; jj < 33; ++jj) {
            const int j = wv * 33 + jj;
            if (j < NDIAG) {
                const float4 w4  = *(const float4*)(&smem[10880 + j * 36 + qg2 * 4]);
                const float4 va  = *(const float4*)(Vb + j * HD + dg * 8);
                const float4 vbx = *(const float4*)(Vb + j * HD + dg * 8 + 4);
                const float wl[4] = {w4.x, w4.y, w4.z, w4.w};
                const float vl[8] = {va.x, va.y, va.z, va.w,
                                     vbx.x, vbx.y, vbx.z, vbx.w};
#pragma unroll
                for (int i = 0; i < 4; ++i) {
                    dacc[i] += wl[i];
#pragma unroll
                    for (int u = 0; u < 8; ++u) acc[i][u] += wl[i] * vl[u];
                }
            }
        }
        // write per-wave partials (Ks region is dead after the phase-1 barrier)
#pragma unroll
        for (int i = 0; i < 4; ++i) {
            const int q = qg2 * 4 + i;
            *(float4*)(&smem[(wv * 32 + q) * 68 + dg * 8]) =
                make_float4(acc[i][0], acc[i][1], acc[i][2], acc[i][3]);
            *(float4*)(&smem[(wv * 32 + q) * 68 + dg * 8 + 4]) =
                make_float4(acc[i][4], acc[i][5], acc[i][6], acc[i][7]);
            if (dg == 0) smem[15632 + wv * 32 + q] = dacc[i];
        }
    }
    __syncthreads();

    // ---- epilogue: combine partials, add Vsum, normalize ----
    {
        const int d = tid & 63;
        const int qg3 = tid >> 6;         // q = qg3*8+i
        const float vs = Vsum[b * HD + d];
#pragma unroll
        for (int i = 0; i < 8; ++i) {
            const int q = qg3 * 8 + i;
            float num = vs;
            float den = 4096.f;
#pragma unroll
            for (int w = 0; w < 4; ++w) {
                num += smem[(w * 32 + q) * 68 + d];
                den += smem[15632 + w * 32 + q];
            }
            out[((size_t)b * NN + n0 + q) * HD + d] = num / den;
        }
    }
}

// ---------------------------------------------------------------------------
extern "C" void kernel_launch(void* const* d_in, const int* in_sizes, int n_in,
                              void* d_out, int out_size, void* d_ws, size_t ws_size,
                              hipStream_t stream)
{
    const float* x  = (const float*)d_in[0];
    const float* Wq = (const float*)d_in[1];
    const float* bq = (const float*)d_in[2];
    const float* Wk = (const float*)d_in[3];
    const float* bk = (const float*)d_in[4];
    const float* Wv = (const float*)d_in[5];
    const float* bv = (const float*)d_in[6];
    float* out = (float*)d_out;

    float* wsf = (float*)d_ws;
    float* Qo = wsf;                 // 524288 floats
    float* Ko = wsf + 524288;        // 524288 floats
    float* Vo = wsf + 1048576;       // 524288 floats
    float* Vs = wsf + 1572864;       // 128 floats

    proj_kernel<<<512, 192, 0, stream>>>(x, Wq, bq, Wk, bk, Wv, bv, Qo, Ko, Vo);
    vsum_kernel<<<2, 1024, 0, stream>>>(Vo, Vs);
    attn_kernel<<<256, 256, 0, stream>>>(Qo, Ko, Vo, Vs, out);
}

// Round 2
// 149.628 us; speedup vs baseline: 1.1141x; 1.1141x over previous
//
#include <hip/hip_runtime.h>

#define NN 4096
#define NE 512
#define HD 64
#define NDIAG 129
#define HWIN 64

// ---------------------------------------------------------------------------
// Kernel 1: fused projections  Q|K|V = x @ W{q,k,v} + b  AND Vsum reduction.
// grid 256 (32 rows/block), block 512 (8 waves; wave = rowgroup of 4 rows,
// lane = output dim d). x chunk staged TRANSPOSED in LDS -> broadcast
// ds_read_b128 (conflict-free, low latency); W read straight from global
// (L1-resident: every wave of every block reads the same 256B lines).
// 12 independent FMA chains/thread for ILP; 8 waves/CU for TLP.
// ---------------------------------------------------------------------------
__global__ __launch_bounds__(512) void proj_kernel(
    const float* __restrict__ x,
    const float* __restrict__ Wq, const float* __restrict__ bq,
    const float* __restrict__ Wk, const float* __restrict__ bk,
    const float* __restrict__ Wv, const float* __restrict__ bv,
    float* __restrict__ Qo, float* __restrict__ Ko, float* __restrict__ Vo,
    float* __restrict__ Vsum)
{
    __shared__ float xs[64][36];     // [k][row], stride 36 floats = 144B (16B-aligned rows)
    __shared__ float vred[512];

    const int tid  = threadIdx.x;
    const int lane = tid & 63;       // output dim d
    const int rg   = tid >> 6;       // rowgroup 0..7 (4 rows each)
    const int r0   = blockIdx.x * 32;

    float acc[3][4];
#pragma unroll
    for (int m = 0; m < 3; ++m)
#pragma unroll
        for (int r = 0; r < 4; ++r) acc[m][r] = 0.f;

    for (int k0 = 0; k0 < NE; k0 += 64) {
        __syncthreads();             // protect xs from previous chunk's readers
        {
            const int r  = tid >> 4;     // 0..31
            const int kq = tid & 15;     // 0..15
            const float4 v = *(const float4*)(x + (size_t)(r0 + r) * NE + k0 + kq * 4);
            xs[kq * 4 + 0][r] = v.x;
            xs[kq * 4 + 1][r] = v.y;
            xs[kq * 4 + 2][r] = v.z;
            xs[kq * 4 + 3][r] = v.w;
        }
        __syncthreads();
#pragma unroll 8
        for (int k = 0; k < 64; ++k) {
            const float4 xr = *(const float4*)(&xs[k][rg * 4]);  // broadcast read
            const int woff = (k0 + k) * HD + lane;               // coalesced 256B
            const float w0 = Wq[woff];
            const float w1 = Wk[woff];
            const float w2 = Wv[woff];
            acc[0][0] += xr.x * w0; acc[0][1] += xr.y * w0;
            acc[0][2] += xr.z * w0; acc[0][3] += xr.w * w0;
            acc[1][0] += xr.x * w1; acc[1][1] += xr.y * w1;
            acc[1][2] += xr.z * w1; acc[1][3] += xr.w * w1;
            acc[2][0] += xr.x * w2; acc[2][1] += xr.y * w2;
            acc[2][2] += xr.z * w2; acc[2][3] += xr.w * w2;
        }
    }

    const float bqv = bq[lane], bkv = bk[lane], bvv = bv[lane];
    const int rbase = r0 + rg * 4;
#pragma unroll
    for (int rr = 0; rr < 4; ++rr) {
        Qo[(size_t)(rbase + rr) * HD + lane] = acc[0][rr] + bqv;
        Ko[(size_t)(rbase + rr) * HD + lane] = acc[1][rr] + bkv;
        Vo[(size_t)(rbase + rr) * HD + lane] = acc[2][rr] + bvv;
    }

    // fused Vsum: sum of this block's 32 V rows (bias included), one atomic/d
    vred[tid] = acc[2][0] + acc[2][1] + acc[2][2] + acc[2][3] + 4.f * bvv;
    __syncthreads();
    if (rg == 0) {
        float s = 0.f;
#pragma unroll
        for (int g = 0; g < 8; ++g) s += vred[g * 64 + lane];
        atomicAdd(&Vsum[(blockIdx.x >> 7) * HD + lane], s);
    }
}

// ---------------------------------------------------------------------------
// Kernel 2: attention. grid 256 (b = blk>>7, 32 queries/block), block 512
// (8 waves = 2/SIMD). out[q,:] = (Vsum + sum_j w[q][j]*V[j,:]) /
// (4096 + sum_j w[q][j]),  w[q][j] = valid(n0+q+j-64) ? exp(Q.K)-1 : 0.
// Phase 2: wave wv exclusively owns queries wv*4..wv*4+3 -> no partial
// combine; weights read as wave-uniform broadcast float4 from LDS.
// ---------------------------------------------------------------------------
__global__ __launch_bounds__(512) void attn_kernel(
    const float* __restrict__ Qf, const float* __restrict__ Kf,
    const float* __restrict__ Vf, const float* __restrict__ Vsum,
    float* __restrict__ out)
{
    __shared__ float Ks[160 * 68];   // K slab, stride 68 floats (16B-aligned rows)
    __shared__ float wt[NDIAG * 36]; // weights j-major, stride 36

    const int tid = threadIdx.x;
    const int b   = blockIdx.x >> 7;
    const int n0  = (blockIdx.x & 127) * 32;

    const float* __restrict__ Qb = Qf + ((size_t)b * NN + n0) * HD;
    const float* __restrict__ Kb = Kf + (size_t)b * NN * HD;
    const float* __restrict__ Vb = Vf + (size_t)b * NN * HD;

    // ---- stage K rows n0-64 .. n0+95 (160 rows, zero-padded at edges) ----
    for (int i = tid; i < 160 * 16; i += 512) {
        const int l = i >> 4, d4 = i & 15;
        const int n = n0 - HWIN + l;
        float4 v = make_float4(0.f, 0.f, 0.f, 0.f);
        if (n >= 0 && n < NN)
            v = *(const float4*)(Kb + (size_t)n * HD + d4 * 4);
        *(float4*)(&Ks[l * 68 + d4 * 4]) = v;
    }
    __syncthreads();

    // ---- phase 1: banded scores -> weights ----
    {
        const int lg = tid & 31;     // l = lg*5+u, u<5
        const int qg = tid >> 5;     // q = qg*2+i, i<2
        float s[2][5];
#pragma unroll
        for (int i = 0; i < 2; ++i)
#pragma unroll
            for (int u = 0; u < 5; ++u) s[i][u] = 0.f;

#pragma unroll 4
        for (int d4 = 0; d4 < 16; ++d4) {
            const float4 q0 = *(const float4*)(Qb + (qg * 2 + 0) * HD + d4 * 4);
            const float4 q1 = *(const float4*)(Qb + (qg * 2 + 1) * HD + d4 * 4);
            float4 kv[5];
#pragma unroll
            for (int u = 0; u < 5; ++u)
                kv[u] = *(const float4*)(&Ks[(lg * 5 + u) * 68 + d4 * 4]);
#pragma unroll
            for (int u = 0; u < 5; ++u) {
                s[0][u] += q0.x * kv[u].x + q0.y * kv[u].y
                         + q0.z * kv[u].z + q0.w * kv[u].w;
                s[1][u] += q1.x * kv[u].x + q1.y * kv[u].y
                         + q1.z * kv[u].z + q1.w * kv[u].w;
            }
        }
#pragma unroll
        for (int i = 0; i < 2; ++i)
#pragma unroll
            for (int u = 0; u < 5; ++u) {
                const int q = qg * 2 + i;
                const int l = lg * 5 + u;
                const int j = l - q;
                if (j >= 0 && j < NDIAG) {
                    const int key = n0 + l - HWIN;
                    float w = 0.f;
                    if (key >= 0 && key < NN)
                        w = __expf(s[i][u]) - 1.f;
                    wt[j * 36 + q] = w;
                }
            }
    }
    __syncthreads();

    // ---- phase 2: wave wv owns queries q0..q0+3; lane = d ----
    {
        const int wv   = tid >> 6;       // 0..7
        const int lane = tid & 63;       // d
        const int q0   = wv * 4;
        float a0 = 0.f, a1 = 0.f, a2 = 0.f, a3 = 0.f;
        float d0 = 0.f, d1 = 0.f, d2 = 0.f, d3 = 0.f;
#pragma unroll 4
        for (int j = 0; j < NDIAG; ++j) {
            const float4 w4 = *(const float4*)(&wt[j * 36 + q0]);  // uniform bcast
            const float vj  = Vb[j * HD + lane];                   // coalesced, L1-hot
            a0 += w4.x * vj; d0 += w4.x;
            a1 += w4.y * vj; d1 += w4.y;
            a2 += w4.z * vj; d2 += w4.z;
            a3 += w4.w * vj; d3 += w4.w;
        }
        const float vs = Vsum[b * HD + lane];
        float* op = out + ((size_t)b * NN + n0 + q0) * HD + lane;
        op[0 * HD] = (vs + a0) / (4096.f + d0);
        op[1 * HD] = (vs + a1) / (4096.f + d1);
        op[2 * HD] = (vs + a2) / (4096.f + d2);
        op[3 * HD] = (vs + a3) / (4096.f + d3);
    }
}

// ---------------------------------------------------------------------------
extern "C" void kernel_launch(void* const* d_in, const int* in_sizes, int n_in,
                              void* d_out, int out_size, void* d_ws, size_t ws_size,
                              hipStream_t stream)
{
    const float* x  = (const float*)d_in[0];
    const float* Wq = (const float*)d_in[1];
    const float* bq = (const float*)d_in[2];
    const float* Wk = (const float*)d_in[3];
    const float* bk = (const float*)d_in[4];
    const float* Wv = (const float*)d_in[5];
    const float* bv = (const float*)d_in[6];
    float* out = (float*)d_out;

    float* wsf = (float*)d_ws;
    float* Qo = wsf;                 // 524288 floats
    float* Ko = wsf + 524288;
    float* Vo = wsf + 1048576;
    float* Vs = wsf + 1572864;       // 128 floats

    hipMemsetAsync(Vs, 0, 128 * sizeof(float), stream);
    proj_kernel<<<256, 512, 0, stream>>>(x, Wq, bq, Wk, bk, Wv, bv, Qo, Ko, Vo, Vs);
    attn_kernel<<<256, 512, 0, stream>>>(Qo, Ko, Vo, Vs, out);
}